// Round 1
// baseline (92.849 us; speedup 1.0000x reference)
//
#include <hip/hip_runtime.h>

#define B_ 128
#define S_ 512
#define H_ 1024
#define L_ 9

// Find position of the r-th (0-based) set bit of m. Caller guarantees popcount(m) > r.
__device__ __forceinline__ int select_bit(unsigned long long m, int r) {
    int pos = 0;
#pragma unroll
    for (int w = 32; w >= 1; w >>= 1) {
        unsigned long long lowmask = ((1ull << w) - 1ull);
        int c = __popcll(m & lowmask);
        if (r >= c) { r -= c; m >>= w; pos += w; }
    }
    return pos;
}

// One block (4 waves) handles 64 consecutive output rows of one batch.
// Wave w computes the partial dot over h in [w*256, w*256+256).
// Lane i owns output row jblock+i entirely (its own gathered source row), so the
// W index depends only on the (uniform) h loop variable -> scalar s_load path.
__global__ __launch_bounds__(256) void ner_kernel(
    const float* __restrict__ seq, const float* __restrict__ W,
    const float* __restrict__ bias, const int* __restrict__ valid,
    float* __restrict__ out) {
    __shared__ float red[4][64][L_];

    const int lane = threadIdx.x & 63;
    const int wv = __builtin_amdgcn_readfirstlane(threadIdx.x >> 6);
    const int b = blockIdx.x >> 3;
    const int jblock = (blockIdx.x & 7) << 6;
    const int tj = jblock + lane;  // this lane's output row within the batch

    // ---- fused stable-compaction: find source index for output row tj ----
    const int* vrow = valid + (size_t)b * S_;
    int src = -1;
    int base = 0;
#pragma unroll
    for (int c = 0; c < 8; ++c) {
        int vv = vrow[c * 64 + lane];
        unsigned long long m = __ballot(vv != 0);
        int cnt = __popcll(m);
        if (src < 0 && tj >= base && tj < base + cnt)
            src = c * 64 + select_bit(m, tj - base);
        base += cnt;
    }
    // tj >= nvalid  =>  src stays -1  =>  row is all-zero pad

    const int hbase = wv << 8;  // this wave's h-quarter
    float acc[L_];
#pragma unroll
    for (int l = 0; l < L_; ++l) acc[l] = 0.f;

    if (src >= 0) {
        const float4* xr =
            reinterpret_cast<const float4*>(seq + ((size_t)b * S_ + src) * H_ + hbase);
        const float* wbase = W + (size_t)hbase * L_;
#pragma unroll 2
        for (int it = 0; it < 64; ++it) {
            float4 xv = xr[it];
            const float* wr = wbase + it * 4 * L_;  // uniform address -> s_load
            float xk[4] = {xv.x, xv.y, xv.z, xv.w};
#pragma unroll
            for (int k = 0; k < 4; ++k) {
#pragma unroll
                for (int l = 0; l < L_; ++l)
                    acc[l] = fmaf(xk[k], wr[k * L_ + l], acc[l]);
            }
        }
    }

#pragma unroll
    for (int l = 0; l < L_; ++l) red[wv][lane][l] = acc[l];
    __syncthreads();

    // ---- wave 0: combine h-quarters, bias + softmax, store ----
    if (threadIdx.x < 64) {
        float v[L_];
#pragma unroll
        for (int l = 0; l < L_; ++l)
            v[l] = red[0][lane][l] + red[1][lane][l] + red[2][lane][l] +
                   red[3][lane][l] + bias[l];
        float mx = v[0];
#pragma unroll
        for (int l = 1; l < L_; ++l) mx = fmaxf(mx, v[l]);
        float s = 0.f;
#pragma unroll
        for (int l = 0; l < L_; ++l) {
            v[l] = expf(v[l] - mx);
            s += v[l];
        }
        float inv = 1.f / s;
        float* orow = out + ((size_t)b * S_ + tj) * L_;
#pragma unroll
        for (int l = 0; l < L_; ++l) orow[l] = v[l] * inv;
    }
}

extern "C" void kernel_launch(void* const* d_in, const int* in_sizes, int n_in,
                              void* d_out, int out_size, void* d_ws, size_t ws_size,
                              hipStream_t stream) {
    const float* seq = (const float*)d_in[0];   // [B,S,H] f32
    const float* W = (const float*)d_in[1];     // [H,L] f32
    const float* bias = (const float*)d_in[2];  // [L] f32
    const int* valid = (const int*)d_in[3];     // [B,S] i32
    float* out = (float*)d_out;                 // [B,S,L] f32

    dim3 grid(B_ * S_ / 64);  // 1024 blocks, 64 output rows each
    ner_kernel<<<grid, 256, 0, stream>>>(seq, W, bias, valid, out);
}

// Round 2
// 53.310 us; speedup vs baseline: 1.7417x; 1.7417x over previous
//
#include <hip/hip_runtime.h>

#define B_ 128
#define S_ 512
#define H_ 1024
#define L_ 9

// Find position of the r-th (0-based) set bit of m. Caller guarantees popcount(m) > r.
__device__ __forceinline__ int select_bit(unsigned long long m, int r) {
    int pos = 0;
#pragma unroll
    for (int w = 32; w >= 1; w >>= 1) {
        unsigned long long lowmask = ((1ull << w) - 1ull);
        int c = __popcll(m & lowmask);
        if (r >= c) { r -= c; m >>= w; pos += w; }
    }
    return pos;
}

// One block (8 waves, 512 threads) handles 64 consecutive output rows of one batch.
// Wave w computes the partial dot over h in [w*128, w*128+128).
// Lane i owns output row jblock+i (its own gathered source row); W index depends
// only on wave-uniform h -> scalar s_load path for W, vector float4 stream for x.
__global__ __launch_bounds__(512, 6) void ner_kernel(
    const float* __restrict__ seq, const float* __restrict__ W,
    const float* __restrict__ bias, const int* __restrict__ valid,
    float* __restrict__ out) {
    __shared__ float red[8][64][L_];

    const int lane = threadIdx.x & 63;
    const int wv = __builtin_amdgcn_readfirstlane(threadIdx.x >> 6);
    const int b = blockIdx.x >> 3;
    const int jblock = (blockIdx.x & 7) << 6;
    const int tj = jblock + lane;  // this lane's output row within the batch

    // ---- fused stable-compaction: find source index for output row tj ----
    // (each wave redundantly computes the identical map; valid row is L1-hot)
    const int* vrow = valid + (size_t)b * S_;
    int src = -1;
    int base = 0;
#pragma unroll
    for (int c = 0; c < 8; ++c) {
        int vv = vrow[c * 64 + lane];
        unsigned long long m = __ballot(vv != 0);
        int cnt = __popcll(m);
        if (src < 0 && tj >= base && tj < base + cnt)
            src = c * 64 + select_bit(m, tj - base);
        base += cnt;
    }
    // tj >= nvalid  =>  src stays -1  =>  row is all-zero pad -> softmax(bias)

    const int hbase = wv << 7;  // this wave's 128-float h-slice
    float acc[L_];
#pragma unroll
    for (int l = 0; l < L_; ++l) acc[l] = 0.f;

    if (src >= 0) {
        const float4* xr =
            reinterpret_cast<const float4*>(seq + ((size_t)b * S_ + src) * H_ + hbase);
        const float* wbase = W + (size_t)hbase * L_;
        // unroll 4: the 4 consecutive float4 loads cover one full 64B line per lane,
        // and give >=4 loads in flight per wave for latency hiding.
#pragma unroll 4
        for (int it = 0; it < 32; ++it) {
            float4 xv = xr[it];
            const float* wr = wbase + it * 4 * L_;  // wave-uniform address -> s_load
            float xk[4] = {xv.x, xv.y, xv.z, xv.w};
#pragma unroll
            for (int k = 0; k < 4; ++k) {
#pragma unroll
                for (int l = 0; l < L_; ++l)
                    acc[l] = fmaf(xk[k], wr[k * L_ + l], acc[l]);
            }
        }
    }

#pragma unroll
    for (int l = 0; l < L_; ++l) red[wv][lane][l] = acc[l];
    __syncthreads();

    // ---- wave 0: combine 8 h-slices, bias + softmax, store ----
    if (threadIdx.x < 64) {
        float v[L_];
#pragma unroll
        for (int l = 0; l < L_; ++l) {
            float s = bias[l];
#pragma unroll
            for (int w = 0; w < 8; ++w) s += red[w][lane][l];
            v[l] = s;
        }
        float mx = v[0];
#pragma unroll
        for (int l = 1; l < L_; ++l) mx = fmaxf(mx, v[l]);
        float s = 0.f;
#pragma unroll
        for (int l = 0; l < L_; ++l) {
            v[l] = expf(v[l] - mx);
            s += v[l];
        }
        float inv = 1.f / s;
        float* orow = out + ((size_t)b * S_ + tj) * L_;
#pragma unroll
        for (int l = 0; l < L_; ++l) orow[l] = v[l] * inv;
    }
}

extern "C" void kernel_launch(void* const* d_in, const int* in_sizes, int n_in,
                              void* d_out, int out_size, void* d_ws, size_t ws_size,
                              hipStream_t stream) {
    const float* seq = (const float*)d_in[0];   // [B,S,H] f32
    const float* W = (const float*)d_in[1];     // [H,L] f32
    const float* bias = (const float*)d_in[2];  // [L] f32
    const int* valid = (const int*)d_in[3];     // [B,S] i32
    float* out = (float*)d_out;                 // [B,S,L] f32

    dim3 grid(B_ * S_ / 64);  // 1024 blocks, 64 output rows each
    ner_kernel<<<grid, 512, 0, stream>>>(seq, W, bias, valid, out);
}

// Round 3
// 39.224 us; speedup vs baseline: 2.3672x; 1.3591x over previous
//
#include <hip/hip_runtime.h>

#define B_ 128
#define S_ 512
#define H_ 1024
#define L_ 9

// Find position of the r-th (0-based) set bit of m. Caller guarantees popcount(m) > r.
__device__ __forceinline__ int select_bit(unsigned long long m, int r) {
    int pos = 0;
#pragma unroll
    for (int w = 32; w >= 1; w >>= 1) {
        unsigned long long lowmask = ((1ull << w) - 1ull);
        int c = __popcll(m & lowmask);
        if (r >= c) { r -= c; m >>= w; pos += w; }
    }
    return pos;
}

// One block (8 waves, 512 threads) handles 64 output rows of one batch, STRIDED:
// slot q (=blockIdx&7) owns rows {q + 8k, k=0..63}, lane k -> row q+8k. Valid rows
// compact to the front (~256/512), so every wave gets ~32 valid + ~32 pad lanes —
// work is balanced across ALL blocks/CUs by construction (dispatch-map independent).
// Wave w computes the partial dot over h in [w*128, w*128+128).
// W index depends only on wave-uniform h -> scalar s_load path; x streams as float4.
__global__ __launch_bounds__(512, 6) void ner_kernel(
    const float* __restrict__ seq, const float* __restrict__ W,
    const float* __restrict__ bias, const int* __restrict__ valid,
    float* __restrict__ out) {
    __shared__ float red[8][64][L_];

    const int lane = threadIdx.x & 63;
    const int wv = __builtin_amdgcn_readfirstlane(threadIdx.x >> 6);
    const int b = blockIdx.x >> 3;
    const int q = blockIdx.x & 7;
    const int tj = q + (lane << 3);  // this lane's output row within the batch

    // ---- fused stable-compaction: find source index for output row tj ----
    const int* vrow = valid + (size_t)b * S_;
    int src = -1;
    int base = 0;
#pragma unroll
    for (int c = 0; c < 8; ++c) {
        int vv = vrow[c * 64 + lane];
        unsigned long long m = __ballot(vv != 0);
        int cnt = __popcll(m);
        if (src < 0 && tj >= base && tj < base + cnt)
            src = c * 64 + select_bit(m, tj - base);
        base += cnt;
    }
    // tj >= nvalid  =>  src stays -1  =>  row is all-zero pad -> softmax(bias)

    const int hbase = wv << 7;  // this wave's 128-float h-slice
    float acc[L_];
#pragma unroll
    for (int l = 0; l < L_; ++l) acc[l] = 0.f;

    if (src >= 0) {
        const float4* xr =
            reinterpret_cast<const float4*>(seq + ((size_t)b * S_ + src) * H_ + hbase);
        const float* wbase = W + (size_t)hbase * L_;
        // unroll 4: the 4 consecutive float4 loads cover one full 64B line per lane,
        // and give >=4 loads in flight per wave for latency hiding.
#pragma unroll 4
        for (int it = 0; it < 32; ++it) {
            float4 xv = xr[it];
            const float* wr = wbase + it * 4 * L_;  // wave-uniform address -> s_load
            float xk[4] = {xv.x, xv.y, xv.z, xv.w};
#pragma unroll
            for (int k = 0; k < 4; ++k) {
#pragma unroll
                for (int l = 0; l < L_; ++l)
                    acc[l] = fmaf(xk[k], wr[k * L_ + l], acc[l]);
            }
        }
    }

#pragma unroll
    for (int l = 0; l < L_; ++l) red[wv][lane][l] = acc[l];
    __syncthreads();

    // ---- wave 0: combine 8 h-slices, bias + softmax, store ----
    if (threadIdx.x < 64) {
        float v[L_];
#pragma unroll
        for (int l = 0; l < L_; ++l) {
            float s = bias[l];
#pragma unroll
            for (int w = 0; w < 8; ++w) s += red[w][lane][l];
            v[l] = s;
        }
        float mx = v[0];
#pragma unroll
        for (int l = 1; l < L_; ++l) mx = fmaxf(mx, v[l]);
        float s = 0.f;
#pragma unroll
        for (int l = 0; l < L_; ++l) {
            v[l] = expf(v[l] - mx);
            s += v[l];
        }
        float inv = 1.f / s;
        float* orow = out + ((size_t)b * S_ + tj) * L_;
#pragma unroll
        for (int l = 0; l < L_; ++l) orow[l] = v[l] * inv;
    }
}

extern "C" void kernel_launch(void* const* d_in, const int* in_sizes, int n_in,
                              void* d_out, int out_size, void* d_ws, size_t ws_size,
                              hipStream_t stream) {
    const float* seq = (const float*)d_in[0];   // [B,S,H] f32
    const float* W = (const float*)d_in[1];     // [H,L] f32
    const float* bias = (const float*)d_in[2];  // [L] f32
    const int* valid = (const int*)d_in[3];     // [B,S] i32
    float* out = (float*)d_out;                 // [B,S,L] f32

    dim3 grid(B_ * S_ / 64);  // 1024 blocks, 64 strided output rows each
    ner_kernel<<<grid, 512, 0, stream>>>(seq, W, bias, valid, out);
}

// Round 4
// 37.547 us; speedup vs baseline: 2.4729x; 1.0447x over previous
//
#include <hip/hip_runtime.h>

#define B_ 128
#define S_ 512
#define H_ 1024
#define L_ 9

// ---------------- Kernel A: per-batch compaction map + pad-row outputs -------
// grid 128 x 64. Block b:
//  - ballot-scan valid[b,:]: ws_src[b*512 + j] = source row of j-th valid token
//  - ws_nv[b] = nv
//  - out[b, j, :] = softmax(bias) for j in [nv, 512)   (pad rows done here)
__global__ __launch_bounds__(64) void prep_kernel(
    const int* __restrict__ valid, const float* __restrict__ bias,
    float* __restrict__ out, int* __restrict__ ws_src, int* __restrict__ ws_nv) {
    const int lane = threadIdx.x;
    const int b = blockIdx.x;
    const int* vrow = valid + (size_t)b * S_;
    int base = 0;
#pragma unroll
    for (int c = 0; c < 8; ++c) {
        int vv = vrow[c * 64 + lane];
        unsigned long long m = __ballot(vv != 0);
        if (vv != 0) {
            int pre = __popcll(m & ((1ull << lane) - 1ull));
            ws_src[b * S_ + base + pre] = c * 64 + lane;
        }
        base += __popcll(m);
    }
    if (lane == 0) ws_nv[b] = base;

    // pad rows get softmax(bias)
    float v[L_];
    float mx = bias[0];
#pragma unroll
    for (int l = 1; l < L_; ++l) mx = fmaxf(mx, bias[l]);
    float s = 0.f;
#pragma unroll
    for (int l = 0; l < L_; ++l) { v[l] = expf(bias[l] - mx); s += v[l]; }
    float inv = 1.f / s;
#pragma unroll
    for (int l = 0; l < L_; ++l) v[l] *= inv;
    for (int j = base + lane; j < S_; j += 64) {
        float* orow = out + ((size_t)b * S_ + j) * L_;
#pragma unroll
        for (int l = 0; l < L_; ++l) orow[l] = v[l];
    }
}

// ---------------- Kernel B: dense GEMM + softmax over the flat valid list ----
// grid 1024 x 256 (4 waves). Global dense index G = blockIdx*64 + lane; binary
// search over the batch prefix (computed per-block from ws_nv via shuffles)
// gives (b, j, src). All 64 lanes are valid rows (except the global tail).
// Wave w covers h in [w*256, w*256+256); W address is wave-uniform -> s_load.
__global__ __launch_bounds__(256, 8) void gemm_kernel(
    const float* __restrict__ seq, const float* __restrict__ W,
    const float* __restrict__ bias, const int* __restrict__ ws_src,
    const int* __restrict__ ws_nv, float* __restrict__ out) {
    __shared__ float red[4][64][L_];
    __shared__ int offs[B_ + 1];

    const int lane = threadIdx.x & 63;
    const int wv = __builtin_amdgcn_readfirstlane(threadIdx.x >> 6);

    // 128-wide exclusive prefix of ws_nv -> offs[0..128] (wave 0 only)
    if (threadIdx.x < 64) {
        int s0 = ws_nv[lane];
        int s1 = ws_nv[64 + lane];
#pragma unroll
        for (int d = 1; d < 64; d <<= 1) {
            int t0 = __shfl_up(s0, d, 64);
            int t1 = __shfl_up(s1, d, 64);
            if (lane >= d) { s0 += t0; s1 += t1; }
        }
        int tot0 = __shfl(s0, 63, 64);
        offs[1 + lane] = s0;
        offs[65 + lane] = tot0 + s1;
        if (lane == 0) offs[0] = 0;
    }
    __syncthreads();

    const int total = offs[B_];
    if (blockIdx.x * 64 >= total) return;  // block-uniform
    const int G = blockIdx.x * 64 + lane;
    const bool active = G < total;

    int b = 0, j = 0, src = 0;
    if (active) {
        int lo = 0, hi = B_;
        while (hi - lo > 1) {
            int mid = (lo + hi) >> 1;
            if (offs[mid] <= G) lo = mid; else hi = mid;
        }
        b = lo;
        j = G - offs[lo];
        src = ws_src[b * S_ + j];
    }

    float acc[L_];
#pragma unroll
    for (int l = 0; l < L_; ++l) acc[l] = 0.f;

    if (active) {
        const int hbase = wv << 8;  // this wave's 256-float h-slice
        const float4* xr =
            reinterpret_cast<const float4*>(seq + ((size_t)b * S_ + src) * H_ + hbase);
        const float* wbase = W + (size_t)hbase * L_;
#pragma unroll 4
        for (int it = 0; it < 64; ++it) {
            float4 xv = xr[it];
            const float* wr = wbase + it * 4 * L_;  // wave-uniform -> s_load
            float xk[4] = {xv.x, xv.y, xv.z, xv.w};
#pragma unroll
            for (int k = 0; k < 4; ++k) {
#pragma unroll
                for (int l = 0; l < L_; ++l)
                    acc[l] = fmaf(xk[k], wr[k * L_ + l], acc[l]);
            }
        }
    }

#pragma unroll
    for (int l = 0; l < L_; ++l) red[wv][lane][l] = acc[l];
    __syncthreads();

    // wave 0: combine 4 h-slices, bias + softmax, store
    if (threadIdx.x < 64 && active) {
        float v[L_];
#pragma unroll
        for (int l = 0; l < L_; ++l)
            v[l] = red[0][lane][l] + red[1][lane][l] + red[2][lane][l] +
                   red[3][lane][l] + bias[l];
        float mx = v[0];
#pragma unroll
        for (int l = 1; l < L_; ++l) mx = fmaxf(mx, v[l]);
        float s = 0.f;
#pragma unroll
        for (int l = 0; l < L_; ++l) {
            v[l] = expf(v[l] - mx);
            s += v[l];
        }
        float inv = 1.f / s;
        float* orow = out + ((size_t)b * S_ + j) * L_;
#pragma unroll
        for (int l = 0; l < L_; ++l) orow[l] = v[l] * inv;
    }
}

extern "C" void kernel_launch(void* const* d_in, const int* in_sizes, int n_in,
                              void* d_out, int out_size, void* d_ws, size_t ws_size,
                              hipStream_t stream) {
    const float* seq = (const float*)d_in[0];   // [B,S,H] f32
    const float* W = (const float*)d_in[1];     // [H,L] f32
    const float* bias = (const float*)d_in[2];  // [L] f32
    const int* valid = (const int*)d_in[3];     // [B,S] i32
    float* out = (float*)d_out;                 // [B,S,L] f32

    int* ws_src = (int*)d_ws;          // [128*512] compacted source indices
    int* ws_nv = ws_src + B_ * S_;     // [128] valid counts

    prep_kernel<<<dim3(B_), dim3(64), 0, stream>>>(valid, bias, out, ws_src, ws_nv);
    gemm_kernel<<<dim3(B_ * S_ / 64), dim3(256), 0, stream>>>(seq, W, bias, ws_src,
                                                              ws_nv, out);
}